// Round 4
// baseline (20602.757 us; speedup 1.0000x reference)
//
#include <hip/hip_runtime.h>
#include <stdint.h>

#define B_ 16
#define T_ 2048
#define I_ 512
#define H_ 512
#define NWG 16          // barrier participants
#define WPG 8           // waves per WG; 128 compute waves total

typedef __bf16 bf16x8 __attribute__((ext_vector_type(8)));
typedef __bf16 bf16x4 __attribute__((ext_vector_type(4)));
typedef float  f32x4  __attribute__((ext_vector_type(4)));

__device__ __forceinline__ float sigm(float x) {
    return __builtin_amdgcn_rcpf(1.f + __builtin_amdgcn_exp2f(-1.44269504f * x));
}
__device__ __forceinline__ float tanh_f(float x) {
    float xc = fmaxf(x, -40.f);
    float e  = __builtin_amdgcn_exp2f(-2.88539008f * xc);
    return (1.f - e) * __builtin_amdgcn_rcpf(1.f + e);
}

// ---- prep: x [B][T][I] fp32 -> xp [T][B][I] bf16 ----
__global__ void pack_x(const float* __restrict__ x, __bf16* __restrict__ xp) {
    int q = blockIdx.x * 256 + threadIdx.x;
    int o = q * 4;
    int i  = o & (I_ - 1);
    int tb = o >> 9;
    int b  = tb & (B_ - 1);
    int t  = tb >> 4;
    float4 v = *(const float4*)(x + ((size_t)(b * T_ + t) * I_ + i));
    *(bf16x4*)(xp + o) = (bf16x4){(__bf16)v.x, (__bf16)v.y, (__bf16)v.z, (__bf16)v.w};
}

// ---- prep: per-rowblock weight pack. wp[rb][n][k], n=0..15: gate g=n>>2, local col=n&3,
//      global row = g*512 + rb*4 + (n&3);  rb = 0..127
__global__ void pack_w(const float* __restrict__ Wi, const float* __restrict__ Wh,
                       __bf16* __restrict__ wip, __bf16* __restrict__ whp) {
    int q = blockIdx.x * 256 + threadIdx.x;   // 2*128*16*128 threads, 4 k each
    int k = (q & 127) * 4;  q >>= 7;
    int n = q & 15;         q >>= 4;
    int rb = q & 127;       q >>= 7;
    int mat = q;
    int row = (n >> 2) * 512 + rb * 4 + (n & 3);
    const float* src = (mat ? Wh : Wi) + (size_t)row * 512 + k;
    float4 v = *(const float4*)src;
    __bf16* dst = (mat ? whp : wip) + ((size_t)(rb * 16 + n) * 512 + k);
    *(bf16x4*)dst = (bf16x4){(__bf16)v.x, (__bf16)v.y, (__bf16)v.z, (__bf16)v.w};
}

// ---- prep: h0 -> hbuf slot0 in [rb][m][4c] bf16 layout; biasp[rb*16+n] = bi+bh ----
__global__ void prep_small(const float* __restrict__ h0, const float* __restrict__ bi,
                           const float* __restrict__ bh, __bf16* __restrict__ hbuf,
                           float* __restrict__ biasp) {
    int i = blockIdx.x * 256 + threadIdx.x;   // 8192 threads
    int rb = i >> 6, m = (i >> 2) & 15, c = i & 3;
    hbuf[i] = (__bf16)h0[m * 512 + rb * 4 + c];
    if (i < 2048) {
        int w = i >> 4, n = i & 15;
        int row = (n >> 2) * 512 + w * 4 + (n & 3);
        biasp[i] = bi[row] + bh[row];
    }
}

// ---- persistent recurrence: 16 WGs x 8 waves ----
__global__ __launch_bounds__(512, 2) void lstm_main(
    const float* __restrict__ c0,
    const __bf16* __restrict__ xp,
    const __bf16* __restrict__ wip,
    const __bf16* __restrict__ whp,
    const float* __restrict__ biasp,
    __bf16* hbuf,                 // [2][128][16][4] bf16  (u64 index rb*16+m)
    unsigned* flags,              // [NWG] monotone, spread 64 B apart
    float* __restrict__ out)
{
    const int w    = blockIdx.x;
    const int u    = threadIdx.x >> 6;
    const int rb   = w * WPG + u;            // 0..127: 16 gate rows = 4 gates x 4 h-cols
    const int lane = threadIdx.x & 63;
    const int quad = lane >> 4;
    const int n16  = lane & 15;

    __shared__ int step_ready;
    if (threadIdx.x == 0) step_ready = 0;
    __syncthreads();

    // weight fragments as A-operand: lane n16 = gate row n, k = kc*32 + quad*8 + j
    bf16x8 bwx[16], bwh[16];
#pragma unroll
    for (int kc = 0; kc < 16; ++kc) {
        size_t idx = ((size_t)(rb * 16 + n16)) * 512 + kc * 32 + quad * 8;
        bwx[kc] = *(const bf16x8*)(wip + idx);
        bwh[kc] = *(const bf16x8*)(whp + idx);
    }
    const float4 b4 = *(const float4*)(biasp + rb * 16 + quad * 4);   // bias for rows quad*4+r

    // c-state on quad-0 lanes: batch = n16, cols rb*4 + r
    float creg[4];
    if (quad == 0) {
        float4 cv0 = *(const float4*)(c0 + (size_t)n16 * H_ + rb * 4);
        creg[0] = cv0.x; creg[1] = cv0.y; creg[2] = cv0.z; creg[3] = cv0.w;
    }

    float* outHT = out + (size_t)B_ * T_ * H_;
    float* outCT = outHT + (size_t)B_ * H_;

    for (int t = 0; t < T_; ++t) {
        // ---- x-side partial (independent of h) ----
        f32x4 accA = {0.f, 0.f, 0.f, 0.f}, accB = {0.f, 0.f, 0.f, 0.f};
        {
            const __bf16* xt = xp + (size_t)t * (B_ * I_) + (size_t)n16 * I_;
#pragma unroll
            for (int kc = 0; kc < 8; ++kc) {
                bf16x8 ax0 = *(const bf16x8*)(xt + kc * 32 + quad * 8);
                bf16x8 ax1 = *(const bf16x8*)(xt + (kc + 8) * 32 + quad * 8);
                accA = __builtin_amdgcn_mfma_f32_16x16x32_bf16(bwx[kc],     ax0, accA, 0, 0, 0);
                accB = __builtin_amdgcn_mfma_f32_16x16x32_bf16(bwx[kc + 8], ax1, accB, 0, 0, 0);
            }
        }

        // ---- hierarchical wait for h_t ----
        if (t > 0) {
            if (u == 0) {
                for (;;) {
                    unsigned f = __hip_atomic_load(flags + (lane & 15) * 16,
                                                   __ATOMIC_RELAXED, __HIP_MEMORY_SCOPE_AGENT);
                    if (__all(f >= (unsigned)t)) break;
                }
                if (lane == 0)
                    __hip_atomic_store(&step_ready, t, __ATOMIC_RELAXED,
                                       __HIP_MEMORY_SCOPE_WORKGROUP);
            }
            while (__hip_atomic_load(&step_ready, __ATOMIC_RELAXED,
                                     __HIP_MEMORY_SCOPE_WORKGROUP) < t) {}
        }

        // ---- h loads (B-operand: lane = batch n16, k = h-col = rb'*4 + c) ----
        const unsigned long long* hr64 =
            (const unsigned long long*)(hbuf + (size_t)(t & 1) * (128 * 64));
        unsigned long long hu[32];
#pragma unroll
        for (int kc = 0; kc < 16; ++kc) {
            int rbp = kc * 8 + quad * 2;              // rowblock of k = kc*32 + quad*8
            hu[2 * kc]     = __hip_atomic_load(hr64 + (size_t)rbp * 16 + n16,
                                               __ATOMIC_RELAXED, __HIP_MEMORY_SCOPE_AGENT);
            hu[2 * kc + 1] = __hip_atomic_load(hr64 + (size_t)(rbp + 1) * 16 + n16,
                                               __ATOMIC_RELAXED, __HIP_MEMORY_SCOPE_AGENT);
        }
#pragma unroll
        for (int kc = 0; kc < 8; ++kc) {
            union { unsigned long long q[2]; bf16x8 v; } a0, a1;
            a0.q[0] = hu[2 * kc];      a0.q[1] = hu[2 * kc + 1];
            a1.q[0] = hu[2 * kc + 16]; a1.q[1] = hu[2 * kc + 17];
            accA = __builtin_amdgcn_mfma_f32_16x16x32_bf16(bwh[kc],     a0.v, accA, 0, 0, 0);
            accB = __builtin_amdgcn_mfma_f32_16x16x32_bf16(bwh[kc + 8], a1.v, accB, 0, 0, 0);
        }
        f32x4 acc = accA + accB;

        // ---- activations: D[row=quad*4+r = gate row][col=n16 = batch]; gate = quad ----
        float hv[4], cv[4];
#pragma unroll
        for (int r = 0; r < 4; ++r) {
            float pre = acc[r] + ((const float*)&b4)[r];
            float a = (quad == 2) ? tanh_f(pre) : sigm(pre);
            float fg = __shfl_xor(a, 16, 64);
            float gg = __shfl_xor(a, 32, 64);
            float og = __shfl_xor(a, 48, 64);
            if (quad == 0) {              // a = input gate; batch n16, cols rb*4 + r
                float c = fg * creg[r] + a * gg;
                creg[r] = c;
                hv[r] = og * tanh_f(c);
                cv[r] = c;
            }
        }

        if (t < T_ - 1) {
            // publish h: one 8 B store per canonical lane (u64 index rb*16 + batch)
            if (quad == 0) {
                union { unsigned short s[4]; unsigned long long q; } hp;
#pragma unroll
                for (int r = 0; r < 4; ++r) {
                    __bf16 hb = (__bf16)hv[r];
                    hp.s[r] = __builtin_bit_cast(unsigned short, hb);
                }
                unsigned long long* hw64 =
                    (unsigned long long*)(hbuf + (size_t)((t + 1) & 1) * (128 * 64));
                __hip_atomic_store(hw64 + (size_t)rb * 16 + n16, hp.q,
                                   __ATOMIC_RELAXED, __HIP_MEMORY_SCOPE_AGENT);
            }
            __threadfence();
            __syncthreads();              // all waves' h-stores drained
            if (threadIdx.x == 0)
                __hip_atomic_store(flags + w * 16, (unsigned)(t + 1),
                                   __ATOMIC_RELEASE, __HIP_MEMORY_SCOPE_AGENT);
        }

        // ---- out[] off the critical path: one 16 B store per canonical lane ----
        if (quad == 0) {
            *(float4*)(out + ((size_t)n16 * T_ + t) * H_ + rb * 4) =
                (float4){hv[0], hv[1], hv[2], hv[3]};
            if (t == T_ - 1) {
                *(float4*)(outHT + (size_t)n16 * H_ + rb * 4) = (float4){hv[0], hv[1], hv[2], hv[3]};
                *(float4*)(outCT + (size_t)n16 * H_ + rb * 4) = (float4){cv[0], cv[1], cv[2], cv[3]};
            }
        }
    }
}

extern "C" void kernel_launch(void* const* d_in, const int* in_sizes, int n_in,
                              void* d_out, int out_size, void* d_ws, size_t ws_size,
                              hipStream_t stream) {
    const float* x  = (const float*)d_in[0];
    const float* h0 = (const float*)d_in[1];
    const float* c0 = (const float*)d_in[2];
    const float* Wi = (const float*)d_in[3];
    const float* bi = (const float*)d_in[4];
    const float* Wh = (const float*)d_in[5];
    const float* bh = (const float*)d_in[6];
    float* out = (float*)d_out;

    char* ws = (char*)d_ws;
    __bf16*   xp    = (__bf16*)ws;                                   // 32 MB
    __bf16*   wip   = (__bf16*)(ws + 33554432);                      // 2 MB
    __bf16*   whp   = (__bf16*)(ws + 35651584);                      // 2 MB
    float*    biasp = (float*) (ws + 37748736);                      // 8 KB
    __bf16*   hbuf  = (__bf16*)(ws + 37756928);                      // 2 x 16 KB
    unsigned* flags = (unsigned*)(ws + 37789696);                    // 1 KB (16 x 64 B)

    hipMemsetAsync(flags, 0, 1024, stream);
    pack_x<<<16384, 256, 0, stream>>>(x, xp);
    pack_w<<<2048, 256, 0, stream>>>(Wi, Wh, wip, whp);
    prep_small<<<32, 256, 0, stream>>>(h0, bi, bh, hbuf, biasp);

    void* args[] = { (void*)&c0, (void*)&xp, (void*)&wip, (void*)&whp, (void*)&biasp,
                     (void*)&hbuf, (void*)&flags, (void*)&out };
    hipLaunchCooperativeKernel((void*)lstm_main, dim3(NWG), dim3(512), args, 0, stream);
}